// Round 13
// baseline (237.290 us; speedup 1.0000x reference)
//
#include <hip/hip_runtime.h>
#include <hip/hip_bf16.h>

#define CI_ 64
#define CO_ 128
#define NPIX 4096
#define CQ_ 16
#define EPS_ 1e-5f

typedef __attribute__((ext_vector_type(8))) __bf16 bf16x8;
typedef __attribute__((ext_vector_type(4))) __bf16 bf16x4;
typedef __attribute__((ext_vector_type(4))) float f32x4;

// a = relu(bn2(Wa @ x + ba)), 4 outputs per thread along n
__global__ __launch_bounds__(256) void z_proj_a4(
    const float* __restrict__ x, const float* __restrict__ Wa, const float* __restrict__ ba,
    const float* __restrict__ g, const float* __restrict__ bb,
    const float* __restrict__ m, const float* __restrict__ v, float* __restrict__ a)
{
    int i = blockIdx.x * 256 + threadIdx.x;
    int n4 = (i & 1023) * 4;
    int co = (i >> 10) & (CO_ - 1);
    int b = i >> 17;
    const float4* xp = (const float4*)(x + (size_t)b * CI_ * NPIX + n4);
    const float* wp = Wa + co * CI_;
    float4 acc;
    acc.x = acc.y = acc.z = acc.w = ba[co];
#pragma unroll 8
    for (int ci = 0; ci < CI_; ++ci) {
        float4 xv = xp[ci * (NPIX / 4)];
        float w = wp[ci];
        acc.x += w * xv.x; acc.y += w * xv.y; acc.z += w * xv.z; acc.w += w * xv.w;
    }
    float sc = rsqrtf(v[co] + EPS_) * g[co];
    float sh = bb[co] - m[co] * sc;
    float4 r;
    r.x = fmaxf(acc.x * sc + sh, 0.f);
    r.y = fmaxf(acc.y * sc + sh, 0.f);
    r.z = fmaxf(acc.z * sc + sh, 0.f);
    r.w = fmaxf(acc.w * sc + sh, 0.f);
    *(float4*)(a + ((size_t)b * CO_ + co) * NPIX + n4) = r;
}

// transpose x -> xT[b][n][ci] bf16
__global__ __launch_bounds__(256) void z_prepx(
    const float* __restrict__ x, __bf16* __restrict__ xT)
{
    __shared__ float tl[64][65];
    int b = blockIdx.x >> 6;
    int n0 = (blockIdx.x & 63) * 64;
    int tid = threadIdx.x;
    int nn = tid & 63, c4 = tid >> 6;
#pragma unroll
    for (int p = 0; p < 16; ++p) {
        int ci = p * 4 + c4;
        tl[ci][nn] = x[((size_t)b * CI_ + ci) * NPIX + n0 + nn];
    }
    __syncthreads();
#pragma unroll
    for (int p = 0; p < 2; ++p) {
        int idx = p * 256 + tid;
        int n = idx >> 3, cig = idx & 7;
        bf16x8 vv;
#pragma unroll
        for (int j = 0; j < 8; ++j) vv[j] = (__bf16)tl[cig * 8 + j][n];
        ((bf16x8*)xT)[((size_t)b * NPIX + n0 + n) * 8 + cig] = vv;
    }
}

// W3 -> Wt2[co][tap*64+ci] bf16
__global__ __launch_bounds__(256) void z_prepw(
    const float* __restrict__ W3, __bf16* __restrict__ Wt2)
{
    int o = blockIdx.x * 256 + threadIdx.x;
    int co = o / 576;
    int r = o - co * 576;
    int tap = r >> 6;
    int ci = r & 63;
    Wt2[o] = (__bf16)W3[((size_t)co * CI_ + ci) * 9 + tap];
}

// Wg (128x256), Wf (128x384), Wr (128x64) -> bf16, concatenated
__global__ __launch_bounds__(256) void z_prepfw(
    const float* __restrict__ Wg, const float* __restrict__ Wf, const float* __restrict__ Wr,
    __bf16* __restrict__ Wb)
{
    int i = blockIdx.x * 256 + threadIdx.x;  // 90112
    float val;
    if (i < 32768) val = Wg[i];
    else if (i < 81920) val = Wf[i - 32768];
    else val = Wr[i - 81920];
    Wb[i] = (__bf16)val;
}

// MFMA implicit-GEMM conv3x3 + BN + ReLU (validated)
__global__ __launch_bounds__(256) void z_conv3m(
    const __bf16* __restrict__ xT, const __bf16* __restrict__ Wt2,
    const float* __restrict__ b3, const float* __restrict__ g,
    const float* __restrict__ bb, const float* __restrict__ m,
    const float* __restrict__ v, float* __restrict__ local)
{
    __shared__ __align__(16) __bf16 xt[3 * 66 * 64];
    __shared__ __align__(16) __bf16 wt[32 * 576];
    __shared__ float scs[32], shs[32];

    int blk = blockIdx.x;
    int b = blk >> 8;
    int h = (blk >> 2) & 63;
    int cg = blk & 3;
    int co0 = cg * 32;
    int tid = threadIdx.x;
    int l = tid & 63;
    int nt = tid >> 6;
    int lm = l & 15, lh = l >> 4;

    if (tid < 32) {
        int co = co0 + tid;
        float scv = rsqrtf(v[co] + EPS_) * g[co];
        scs[tid] = scv;
        shs[tid] = (b3[co] - m[co]) * scv + bb[co];
    }

    const bf16x8* xs = (const bf16x8*)xT + (size_t)b * (NPIX * 8);
    for (int i = tid; i < 1584; i += 256) {
        int r = i / 528;
        int rem = i - r * 528;
        int c = rem >> 3;
        int cig = rem & 7;
        int hh = h + r - 1;
        int gc = c - 1;
        bf16x8 val;
#pragma unroll
        for (int j = 0; j < 8; ++j) val[j] = (__bf16)0.f;
        if ((unsigned)hh < 64u && (unsigned)gc < 64u)
            val = xs[(hh * 64 + gc) * 8 + cig];
        *(bf16x8*)&xt[(r * 66 + c) * 64 + ((cig ^ (c & 7)) * 8)] = val;
    }
    const bf16x8* wsrc = (const bf16x8*)Wt2 + (size_t)co0 * 72;
    for (int i = tid; i < 2304; i += 256) {
        int co = i / 72;
        int kc = i - co * 72;
        *(bf16x8*)&wt[co * 576 + ((kc ^ (co & 7)) * 8)] = wsrc[i];
    }
    __syncthreads();

    f32x4 acc0 = {0.f, 0.f, 0.f, 0.f};
    f32x4 acc1 = {0.f, 0.f, 0.f, 0.f};
#pragma unroll
    for (int tap = 0; tap < 9; ++tap) {
        int dh = tap / 3, dw = tap % 3;
#pragma unroll
        for (int ks = 0; ks < 2; ++ks) {
            int cig = ks * 4 + lh;
            int col = nt * 16 + lm + dw;
            bf16x8 bfr = *(const bf16x8*)&xt[(dh * 66 + col) * 64 + ((cig ^ (col & 7)) * 8)];
            int kcg = tap * 8 + cig;
            bf16x8 a0 = *(const bf16x8*)&wt[lm * 576 + ((kcg ^ (lm & 7)) * 8)];
            bf16x8 a1 = *(const bf16x8*)&wt[(16 + lm) * 576 + ((kcg ^ (lm & 7)) * 8)];
            acc0 = __builtin_amdgcn_mfma_f32_16x16x32_bf16(a0, bfr, acc0, 0, 0, 0);
            acc1 = __builtin_amdgcn_mfma_f32_16x16x32_bf16(a1, bfr, acc1, 0, 0, 0);
        }
    }

    size_t obase = (size_t)b * CO_ * NPIX + h * 64 + nt * 16 + lm;
#pragma unroll
    for (int r = 0; r < 4; ++r) {
        int cl0 = lh * 4 + r;
        float y0 = fmaxf(acc0[r] * scs[cl0] + shs[cl0], 0.f);
        local[obase + (size_t)(co0 + cl0) * NPIX] = y0;
        int cl1 = 16 + cl0;
        float y1 = fmaxf(acc1[r] * scs[cl1] + shs[cl1], 0.f);
        local[obase + (size_t)(co0 + cl1) * NPIX] = y1;
    }
}

// q projection (Cout=16), fp32
__global__ __launch_bounds__(256) void z_projqk(
    const float* __restrict__ a, const float* __restrict__ W, const float* __restrict__ bias,
    float* __restrict__ out)
{
    int i = blockIdx.x * 256 + threadIdx.x;
    int n = i & (NPIX - 1);
    int c = (i >> 12) & (CQ_ - 1);
    int b = i >> 16;
    const float* ap = a + (size_t)b * CO_ * NPIX + n;
    const float* wp = W + c * CO_;
    float acc = bias[c];
#pragma unroll 8
    for (int t = 0; t < CO_; ++t) acc += wp[t] * ap[t * NPIX];
    out[i] = acc;
}

// k projection -> transposed bf16 kT[b][n][16]
__global__ __launch_bounds__(256) void z_projkT(
    const float* __restrict__ a, const float* __restrict__ W, const float* __restrict__ bias,
    __bf16* __restrict__ kT)
{
    int i = blockIdx.x * 256 + threadIdx.x;
    int n = i & (NPIX - 1);
    int c = (i >> 12) & (CQ_ - 1);
    int b = i >> 16;
    const float* ap = a + (size_t)b * CO_ * NPIX + n;
    const float* wp = W + c * CO_;
    float acc = bias[c];
#pragma unroll 8
    for (int t = 0; t < CO_; ++t) acc += wp[t] * ap[t * NPIX];
    kT[((size_t)b * NPIX + n) * CQ_ + c] = (__bf16)acc;
}

// V2[b][n/8][c][8] bf16 (MFMA B-fragment layout)
__global__ __launch_bounds__(256) void z_projv2(
    const float* __restrict__ a, const float* __restrict__ Wv, const float* __restrict__ bv,
    __bf16* __restrict__ V2)
{
    __shared__ __bf16 wsm[128 * 130];
    int tid = threadIdx.x;
    int blk = blockIdx.x;
    int b = blk >> 8;
    int ng = blk & 255;

    for (int i = tid; i < 128 * 128; i += 256) {
        int c = i >> 7, t = i & 127;
        wsm[c * 130 + t] = (__bf16)Wv[i];
    }
    __syncthreads();

    int c = tid & 127;
    int n8 = ng * 2 + (tid >> 7);
    float acc[8];
    float bvc = bv[c];
#pragma unroll
    for (int j = 0; j < 8; ++j) acc[j] = bvc;

    const float4* a4 = (const float4*)(a + (size_t)b * CO_ * NPIX);
#pragma unroll 4
    for (int t = 0; t < 128; ++t) {
        float w = (float)wsm[c * 130 + t];
        float4 a0 = a4[t * 1024 + n8 * 2];
        float4 a1 = a4[t * 1024 + n8 * 2 + 1];
        acc[0] += w * a0.x; acc[1] += w * a0.y; acc[2] += w * a0.z; acc[3] += w * a0.w;
        acc[4] += w * a1.x; acc[5] += w * a1.y; acc[6] += w * a1.z; acc[7] += w * a1.w;
    }
    bf16x8 r;
#pragma unroll
    for (int j = 0; j < 8; ++j) r[j] = (__bf16)acc[j];
    ((bf16x8*)V2)[(size_t)b * 65536 + n8 * 128 + c] = r;
}

// wave-independent MFMA flash attention: 4 waves x 16 queries, no barriers in loop.
__global__ __launch_bounds__(256) void z_attn5(
    const float* __restrict__ q, const __bf16* __restrict__ kT, const __bf16* __restrict__ V2,
    const float* __restrict__ a, const float* __restrict__ gamp, float* __restrict__ attn)
{
    __shared__ __align__(16) unsigned char smem[4 * 8768];   // per-wave: P (8448B) / o (8704B)
    int tid = threadIdx.x;
    int b = blockIdx.x >> 6;
    int w = tid >> 6;
    int q0 = (blockIdx.x & 63) * 64 + w * 16;
    int l = tid & 63;
    int lm = l & 15, g = l >> 4;
    __bf16* p_lds = (__bf16*)(smem + w * 8768);

    // Q B-fragment (zero-padded K 16..31)
    bf16x8 qfrag;
#pragma unroll
    for (int j = 0; j < 8; ++j) qfrag[j] = (__bf16)0.f;
    if (g < 2) {
#pragma unroll
        for (int j = 0; j < 8; ++j)
            qfrag[j] = (__bf16)q[((size_t)b * CQ_ + g * 8 + j) * NPIX + q0 + lm];
    }

    float m_run = -1e30f, l_run = 0.f;
    f32x4 acc[8];
#pragma unroll
    for (int j = 0; j < 8; ++j) acc[j] = (f32x4){0.f, 0.f, 0.f, 0.f};
    const bf16x8* vbase = (const bf16x8*)V2 + (size_t)b * 65536;
    const __bf16* ktb = kT + (size_t)b * NPIX * CQ_;

    for (int t = 0; t < 16; ++t) {
        int m0 = t * 256;
        // QK^T: 16 m-subtiles
        f32x4 sfr[16];
#pragma unroll
        for (int ms = 0; ms < 16; ++ms) {
            bf16x8 kf;
#pragma unroll
            for (int j = 0; j < 8; ++j) kf[j] = (__bf16)0.f;
            if (g < 2)
                kf = *(const bf16x8*)&ktb[(size_t)(m0 + ms * 16 + lm) * CQ_ + g * 8];
            f32x4 zz = {0.f, 0.f, 0.f, 0.f};
            sfr[ms] = __builtin_amdgcn_mfma_f32_16x16x32_bf16(kf, qfrag, zz, 0, 0, 0);
        }
        // row max (query = lm), wave-internal
        float pmax = -1e30f;
#pragma unroll
        for (int ms = 0; ms < 16; ++ms)
#pragma unroll
            for (int r = 0; r < 4; ++r) pmax = fmaxf(pmax, sfr[ms][r]);
        pmax = fmaxf(pmax, __shfl_xor(pmax, 16));
        pmax = fmaxf(pmax, __shfl_xor(pmax, 32));
        float nm = fmaxf(m_run, pmax);
        float f = __expf(m_run - nm);
        m_run = nm;
        // exp + pack bf16 + partial sum
        float psum = 0.f;
#pragma unroll
        for (int ms = 0; ms < 16; ++ms) {
            float p0 = __expf(sfr[ms][0] - nm);
            float p1 = __expf(sfr[ms][1] - nm);
            float p2 = __expf(sfr[ms][2] - nm);
            float p3 = __expf(sfr[ms][3] - nm);
            psum += (p0 + p1) + (p2 + p3);
            bf16x4 pk;
            pk[0] = (__bf16)p0; pk[1] = (__bf16)p1; pk[2] = (__bf16)p2; pk[3] = (__bf16)p3;
            *(bf16x4*)&p_lds[lm * 264 + ms * 16 + g * 4] = pk;
        }
        psum += __shfl_xor(psum, 16);
        psum += __shfl_xor(psum, 32);
        l_run = l_run * f + psum;
        // rescale factors for rows g*4+r (query index < 16 → lanes 0..15 hold them)
        float fr[4];
#pragma unroll
        for (int r = 0; r < 4; ++r) fr[r] = __shfl(f, g * 4 + r);
#pragma unroll
        for (int j = 0; j < 8; ++j) {
#pragma unroll
            for (int r = 0; r < 4; ++r) acc[j][r] *= fr[r];
        }
        // PV: K=256 in 8 chunks, 8 channel groups
#pragma unroll
        for (int kc = 0; kc < 8; ++kc) {
            bf16x8 af = *(const bf16x8*)&p_lds[lm * 264 + kc * 32 + g * 8];
            int msv = (m0 >> 3) + kc * 4 + g;
#pragma unroll
            for (int j = 0; j < 8; ++j) {
                bf16x8 bf = vbase[msv * 128 + j * 16 + lm];
                acc[j] = __builtin_amdgcn_mfma_f32_16x16x32_bf16(af, bf, acc[j], 0, 0, 0);
            }
        }
    }

    // epilogue (wave-private)
    float* o_lds = (float*)(smem + w * 8768);
    float linv = 1.f / l_run;
    float ir[4];
#pragma unroll
    for (int r = 0; r < 4; ++r) ir[r] = __shfl(linv, g * 4 + r);
#pragma unroll
    for (int j = 0; j < 8; ++j)
#pragma unroll
        for (int r = 0; r < 4; ++r)
            o_lds[(j * 16 + lm) * 17 + g * 4 + r] = acc[j][r] * ir[r];
    __builtin_amdgcn_s_waitcnt(0);   // lgkm drain (same-wave ds ordering)
    float gam = gamp[0];
    int qi = l & 15;
    int cg = l >> 4;
#pragma unroll
    for (int j = 0; j < 32; ++j) {
        int c = cg + j * 4;
        size_t idx = ((size_t)b * CO_ + c) * NPIX + q0 + qi;
        attn[idx] = gam * o_lds[c * 17 + qi] + a[idx];
    }
}

// fused gate + final, MFMA everywhere.
// block = (b, 32-col n-tile); sb2[n][k] bf16, XOR-swizzled 16B chunks.
__global__ __launch_bounds__(256) void z_fuseout2(
    const float* __restrict__ local, const float* __restrict__ attn, const float* __restrict__ x,
    const __bf16* __restrict__ Wb,
    const float* __restrict__ bg, const float* __restrict__ g3, const float* __restrict__ b3n,
    const float* __restrict__ m3, const float* __restrict__ v3,
    const float* __restrict__ bfb, const float* __restrict__ g4, const float* __restrict__ b4,
    const float* __restrict__ m4, const float* __restrict__ v4,
    const float* __restrict__ rsp, float* __restrict__ out)
{
    __shared__ __align__(16) unsigned char smem[32768 + 4096];
    __bf16* sb2 = (__bf16*)smem;             // 32 x 448 (k: fused 0..127, local 128..255, attn 256..383)
    __bf16* sxT = (__bf16*)(smem + 28672);   // 32 x 64

    int tid = threadIdx.x;
    int b = blockIdx.x >> 7;
    int n0 = (blockIdx.x & 127) * 32;

    // stage local/attn transposed bf16 with chunk swizzle
#pragma unroll
    for (int p = 0; p < 4; ++p) {
        int idx = p * 256 + tid;
        int c = idx >> 3, j = idx & 7;
        float lv[4], av[4];
        *(float4*)lv = *(const float4*)(local + ((size_t)b * CO_ + c) * NPIX + n0 + j * 4);
        *(float4*)av = *(const float4*)(attn + ((size_t)b * CO_ + c) * NPIX + n0 + j * 4);
#pragma unroll
        for (int e = 0; e < 4; ++e) {
            int n = j * 4 + e;
            int k1 = 128 + c, k2 = 256 + c;
            sb2[n * 448 + (((k1 >> 3) ^ (n & 7)) << 3) + (k1 & 7)] = (__bf16)lv[e];
            sb2[n * 448 + (((k2 >> 3) ^ (n & 7)) << 3) + (k2 & 7)] = (__bf16)av[e];
        }
    }
#pragma unroll
    for (int p = 0; p < 2; ++p) {
        int idx = p * 256 + tid;
        int c = idx >> 3, j = idx & 7;
        float xv[4];
        *(float4*)xv = *(const float4*)(x + ((size_t)b * CI_ + c) * NPIX + n0 + j * 4);
#pragma unroll
        for (int e = 0; e < 4; ++e) {
            int n = j * 4 + e;
            sxT[n * 64 + (((c >> 3) ^ (n & 7)) << 3) + (c & 7)] = (__bf16)xv[e];
        }
    }
    __syncthreads();

    int l = tid & 63, w = tid >> 6;
    int lm = l & 15, g = l >> 4;
    int co0 = w * 32;
    int t7 = lm & 7;

    // ---- phase 1: gate GEMM (K=256 over sb2 k 128..383) ----
    f32x4 p1[2][2];
#pragma unroll
    for (int cs = 0; cs < 2; ++cs) {
        float bv = bg[co0 + cs * 16 + lm];
#pragma unroll
        for (int ns = 0; ns < 2; ++ns) {
            p1[ns][cs][0] = bv; p1[ns][cs][1] = bv; p1[ns][cs][2] = bv; p1[ns][cs][3] = bv;
        }
    }
    const __bf16* Wg2 = Wb;
#pragma unroll
    for (int kc = 0; kc < 8; ++kc) {
        int ch = (16 + kc * 4 + g) ^ t7;
        bf16x8 a0 = *(const bf16x8*)&sb2[lm * 448 + ch * 8];
        bf16x8 a1 = *(const bf16x8*)&sb2[(16 + lm) * 448 + ch * 8];
        bf16x8 b0 = *(const bf16x8*)&Wg2[(size_t)(co0 + lm) * 256 + kc * 32 + g * 8];
        bf16x8 b1 = *(const bf16x8*)&Wg2[(size_t)(co0 + 16 + lm) * 256 + kc * 32 + g * 8];
        p1[0][0] = __builtin_amdgcn_mfma_f32_16x16x32_bf16(a0, b0, p1[0][0], 0, 0, 0);
        p1[0][1] = __builtin_amdgcn_mfma_f32_16x16x32_bf16(a0, b1, p1[0][1], 0, 0, 0);
        p1[1][0] = __builtin_amdgcn_mfma_f32_16x16x32_bf16(a1, b0, p1[1][0], 0, 0, 0);
        p1[1][1] = __builtin_amdgcn_mfma_f32_16x16x32_bf16(a1, b1, p1[1][1], 0, 0, 0);
    }
    // gate -> fused into sb2 k 0..127
#pragma unroll
    for (int cs = 0; cs < 2; ++cs) {
        int co = co0 + cs * 16 + lm;
        float sc3 = rsqrtf(v3[co] + EPS_) * g3[co];
        float sh3 = b3n[co] - m3[co] * sc3;
        int kl = 128 + co, ka = 256 + co;
#pragma unroll
        for (int ns = 0; ns < 2; ++ns)
#pragma unroll
            for (int r = 0; r < 4; ++r) {
                int n = ns * 16 + g * 4 + r;
                float z = p1[ns][cs][r] * sc3 + sh3;
                float gate = 1.f / (1.f + __expf(-z));
                float lv = (float)sb2[n * 448 + (((kl >> 3) ^ (n & 7)) << 3) + (kl & 7)];
                float av = (float)sb2[n * 448 + (((ka >> 3) ^ (n & 7)) << 3) + (ka & 7)];
                float fu = gate * lv + (1.f - gate) * av;
                sb2[n * 448 + (((co >> 3) ^ (n & 7)) << 3) + (co & 7)] = (__bf16)fu;
            }
    }
    __syncthreads();

    // ---- phase 2: Wf (K=384) + Wr (K=64) ----
    f32x4 p2[2][2], pr[2][2];
#pragma unroll
    for (int cs = 0; cs < 2; ++cs) {
        float bv = bfb[co0 + cs * 16 + lm];
#pragma unroll
        for (int ns = 0; ns < 2; ++ns) {
            p2[ns][cs][0] = bv; p2[ns][cs][1] = bv; p2[ns][cs][2] = bv; p2[ns][cs][3] = bv;
            pr[ns][cs] = (f32x4){0.f, 0.f, 0.f, 0.f};
        }
    }
    const __bf16* Wf2 = Wb + 32768;
    const __bf16* Wr2 = Wb + 81920;
#pragma unroll
    for (int kc = 0; kc < 12; ++kc) {
        int ch = (kc * 4 + g) ^ t7;
        bf16x8 a0 = *(const bf16x8*)&sb2[lm * 448 + ch * 8];
        bf16x8 a1 = *(const bf16x8*)&sb2[(16 + lm) * 448 + ch * 8];
        bf16x8 b0 = *(const bf16x8*)&Wf2[(size_t)(co0 + lm) * 384 + kc * 32 + g * 8];
        bf16x8 b1 = *(const bf16x8*)&Wf2[(size_t)(co0 + 16 + lm) * 384 + kc * 32 + g * 8];
        p2[0][0] = __builtin_amdgcn_mfma_f32_16x16x32_bf16(a0, b0, p2[0][0], 0, 0, 0);
        p2[0][1] = __builtin_amdgcn_mfma_f32_16x16x32_bf16(a0, b1, p2[0][1], 0, 0, 0);
        p2[1][0] = __builtin_amdgcn_mfma_f32_16x16x32_bf16(a1, b0, p2[1][0], 0, 0, 0);
        p2[1][1] = __builtin_amdgcn_mfma_f32_16x16x32_bf16(a1, b1, p2[1][1], 0, 0, 0);
    }
#pragma unroll
    for (int kc = 0; kc < 2; ++kc) {
        int ch = (kc * 4 + g) ^ t7;
        bf16x8 a0 = *(const bf16x8*)&sxT[lm * 64 + ch * 8];
        bf16x8 a1 = *(const bf16x8*)&sxT[(16 + lm) * 64 + ch * 8];
        bf16x8 b0 = *(const bf16x8*)&Wr2[(size_t)(co0 + lm) * 64 + kc * 32 + g * 8];
        bf16x8 b1 = *(const bf16x8*)&Wr2[(size_t)(co0 + 16 + lm) * 64 + kc * 32 + g * 8];
        pr[0][0] = __builtin_amdgcn_mfma_f32_16x16x32_bf16(a0, b0, pr[0][0], 0, 0, 0);
        pr[0][1] = __builtin_amdgcn_mfma_f32_16x16x32_bf16(a0, b1, pr[0][1], 0, 0, 0);
        pr[1][0] = __builtin_amdgcn_mfma_f32_16x16x32_bf16(a1, b0, pr[1][0], 0, 0, 0);
        pr[1][1] = __builtin_amdgcn_mfma_f32_16x16x32_bf16(a1, b1, pr[1][1], 0, 0, 0);
    }
    __syncthreads();   // sb2 reads done; o_lds aliases sb2

    float* o_lds = (float*)smem;   // [128][36]
    float rsv = rsp[0];
#pragma unroll
    for (int cs = 0; cs < 2; ++cs) {
        int co = co0 + cs * 16 + lm;
        float sc4 = rsqrtf(v4[co] + EPS_) * g4[co];
        float sh4 = b4[co] - m4[co] * sc4;
#pragma unroll
        for (int ns = 0; ns < 2; ++ns)
#pragma unroll
            for (int r = 0; r < 4; ++r) {
                int n = ns * 16 + g * 4 + r;
                float o = fmaxf(p2[ns][cs][r] * sc4 + sh4, 0.f) + rsv * pr[ns][cs][r];
                o_lds[co * 36 + n] = o;
            }
    }
    __syncthreads();
    {
        int c = tid >> 1, h = tid & 1;
#pragma unroll
        for (int j2 = 0; j2 < 4; ++j2) {
            float4 vv = *(float4*)&o_lds[c * 36 + h * 16 + j2 * 4];
            *(float4*)(out + ((size_t)b * CO_ + c) * NPIX + n0 + h * 16 + j2 * 4) = vv;
        }
    }
}

extern "C" void kernel_launch(void* const* d_in, const int* in_sizes, int n_in,
                              void* d_out, int out_size, void* d_ws, size_t ws_size,
                              hipStream_t stream) {
    const float* x   = (const float*)d_in[0];
    const float* W3  = (const float*)d_in[1];
    const float* b3  = (const float*)d_in[2];
    const float* g1  = (const float*)d_in[3];
    const float* b1  = (const float*)d_in[4];
    const float* m1  = (const float*)d_in[5];
    const float* v1  = (const float*)d_in[6];
    const float* Wa  = (const float*)d_in[7];
    const float* ba  = (const float*)d_in[8];
    const float* g2  = (const float*)d_in[9];
    const float* b2  = (const float*)d_in[10];
    const float* m2  = (const float*)d_in[11];
    const float* v2  = (const float*)d_in[12];
    const float* Wq  = (const float*)d_in[13];
    const float* bq  = (const float*)d_in[14];
    const float* Wk  = (const float*)d_in[15];
    const float* bk  = (const float*)d_in[16];
    const float* Wv  = (const float*)d_in[17];
    const float* bv  = (const float*)d_in[18];
    const float* gam = (const float*)d_in[19];
    const float* Wg  = (const float*)d_in[20];
    const float* bg  = (const float*)d_in[21];
    const float* g3  = (const float*)d_in[22];
    const float* b3n = (const float*)d_in[23];
    const float* m3  = (const float*)d_in[24];
    const float* v3  = (const float*)d_in[25];
    const float* Wf  = (const float*)d_in[26];
    const float* bfb = (const float*)d_in[27];
    const float* g4  = (const float*)d_in[28];
    const float* b4  = (const float*)d_in[29];
    const float* m4  = (const float*)d_in[30];
    const float* v4  = (const float*)d_in[31];
    const float* Wr  = (const float*)d_in[32];
    const float* rs  = (const float*)d_in[33];

    float* ws    = (float*)d_ws;
    float* a_    = ws;                       // [0, 2M)
    float* local = ws + 2097152;             // [2M, 4M)
    float* attn  = ws + 4194304;             // [4M, 6M)
    __bf16* V2   = (__bf16*)(ws + 6291456);  // 4 MB bf16
    float* q     = ws + 7340032;             // 262,144 floats
    __bf16* kT   = (__bf16*)(ws + 7602176);  // 512 KB bf16
    __bf16* xT   = (__bf16*)(ws + 7864320);  // 2 MB bf16
    __bf16* Wt2  = (__bf16*)(ws + 8388608);  // 147 KB bf16
    __bf16* Wb   = (__bf16*)(ws + 8450048);  // 180 KB bf16 (90,112 elems)

    float* out = (float*)d_out;

    z_prepx<<<256, 256, 0, stream>>>(x, xT);
    z_prepw<<<288, 256, 0, stream>>>(W3, Wt2);
    z_prepfw<<<352, 256, 0, stream>>>(Wg, Wf, Wr, Wb);
    z_proj_a4<<<2048, 256, 0, stream>>>(x, Wa, ba, g2, b2, m2, v2, a_);
    z_projqk<<<1024, 256, 0, stream>>>(a_, Wq, bq, q);
    z_projkT<<<1024, 256, 0, stream>>>(a_, Wk, bk, kT);
    z_projv2<<<1024, 256, 0, stream>>>(a_, Wv, bv, V2);
    z_attn5<<<256, 256, 0, stream>>>(q, kT, V2, a_, gam, attn);
    z_conv3m<<<1024, 256, 0, stream>>>(xT, Wt2, b3, g1, b1, m1, v1, local);
    z_fuseout2<<<512, 256, 0, stream>>>(local, attn, x, Wb, bg, g3, b3n, m3, v3,
                                        bfb, g4, b4, m4, v4, rs, out);
}

// Round 14
// 215.382 us; speedup vs baseline: 1.1017x; 1.1017x over previous
//
#include <hip/hip_runtime.h>
#include <hip/hip_bf16.h>

#define CI_ 64
#define CO_ 128
#define NPIX 4096
#define CQ_ 16
#define EPS_ 1e-5f

typedef __attribute__((ext_vector_type(8))) __bf16 bf16x8;
typedef __attribute__((ext_vector_type(4))) __bf16 bf16x4;
typedef __attribute__((ext_vector_type(4))) float f32x4;

// a = relu(bn2(Wa @ x + ba)), 4 outputs per thread along n
__global__ __launch_bounds__(256) void z_proj_a4(
    const float* __restrict__ x, const float* __restrict__ Wa, const float* __restrict__ ba,
    const float* __restrict__ g, const float* __restrict__ bb,
    const float* __restrict__ m, const float* __restrict__ v, float* __restrict__ a)
{
    int i = blockIdx.x * 256 + threadIdx.x;
    int n4 = (i & 1023) * 4;
    int co = (i >> 10) & (CO_ - 1);
    int b = i >> 17;
    const float4* xp = (const float4*)(x + (size_t)b * CI_ * NPIX + n4);
    const float* wp = Wa + co * CI_;
    float4 acc;
    acc.x = acc.y = acc.z = acc.w = ba[co];
#pragma unroll 8
    for (int ci = 0; ci < CI_; ++ci) {
        float4 xv = xp[ci * (NPIX / 4)];
        float w = wp[ci];
        acc.x += w * xv.x; acc.y += w * xv.y; acc.z += w * xv.z; acc.w += w * xv.w;
    }
    float sc = rsqrtf(v[co] + EPS_) * g[co];
    float sh = bb[co] - m[co] * sc;
    float4 r;
    r.x = fmaxf(acc.x * sc + sh, 0.f);
    r.y = fmaxf(acc.y * sc + sh, 0.f);
    r.z = fmaxf(acc.z * sc + sh, 0.f);
    r.w = fmaxf(acc.w * sc + sh, 0.f);
    *(float4*)(a + ((size_t)b * CO_ + co) * NPIX + n4) = r;
}

// transpose x -> xT[b][n][ci] bf16
__global__ __launch_bounds__(256) void z_prepx(
    const float* __restrict__ x, __bf16* __restrict__ xT)
{
    __shared__ float tl[64][65];
    int b = blockIdx.x >> 6;
    int n0 = (blockIdx.x & 63) * 64;
    int tid = threadIdx.x;
    int nn = tid & 63, c4 = tid >> 6;
#pragma unroll
    for (int p = 0; p < 16; ++p) {
        int ci = p * 4 + c4;
        tl[ci][nn] = x[((size_t)b * CI_ + ci) * NPIX + n0 + nn];
    }
    __syncthreads();
#pragma unroll
    for (int p = 0; p < 2; ++p) {
        int idx = p * 256 + tid;
        int n = idx >> 3, cig = idx & 7;
        bf16x8 vv;
#pragma unroll
        for (int j = 0; j < 8; ++j) vv[j] = (__bf16)tl[cig * 8 + j][n];
        ((bf16x8*)xT)[((size_t)b * NPIX + n0 + n) * 8 + cig] = vv;
    }
}

// W3 -> Wt2[co][tap*64+ci] bf16
__global__ __launch_bounds__(256) void z_prepw(
    const float* __restrict__ W3, __bf16* __restrict__ Wt2)
{
    int o = blockIdx.x * 256 + threadIdx.x;
    int co = o / 576;
    int r = o - co * 576;
    int tap = r >> 6;
    int ci = r & 63;
    Wt2[o] = (__bf16)W3[((size_t)co * CI_ + ci) * 9 + tap];
}

// Wg, Wf, Wr -> bf16 concatenated
__global__ __launch_bounds__(256) void z_prepfw(
    const float* __restrict__ Wg, const float* __restrict__ Wf, const float* __restrict__ Wr,
    __bf16* __restrict__ Wb)
{
    int i = blockIdx.x * 256 + threadIdx.x;  // 90112
    float val;
    if (i < 32768) val = Wg[i];
    else if (i < 81920) val = Wf[i - 32768];
    else val = Wr[i - 81920];
    Wb[i] = (__bf16)val;
}

// MFMA implicit-GEMM conv3x3 + BN + ReLU (validated)
__global__ __launch_bounds__(256) void z_conv3m(
    const __bf16* __restrict__ xT, const __bf16* __restrict__ Wt2,
    const float* __restrict__ b3, const float* __restrict__ g,
    const float* __restrict__ bb, const float* __restrict__ m,
    const float* __restrict__ v, float* __restrict__ local)
{
    __shared__ __align__(16) __bf16 xt[3 * 66 * 64];
    __shared__ __align__(16) __bf16 wt[32 * 576];
    __shared__ float scs[32], shs[32];

    int blk = blockIdx.x;
    int b = blk >> 8;
    int h = (blk >> 2) & 63;
    int cg = blk & 3;
    int co0 = cg * 32;
    int tid = threadIdx.x;
    int l = tid & 63;
    int nt = tid >> 6;
    int lm = l & 15, lh = l >> 4;

    if (tid < 32) {
        int co = co0 + tid;
        float scv = rsqrtf(v[co] + EPS_) * g[co];
        scs[tid] = scv;
        shs[tid] = (b3[co] - m[co]) * scv + bb[co];
    }

    const bf16x8* xs = (const bf16x8*)xT + (size_t)b * (NPIX * 8);
    for (int i = tid; i < 1584; i += 256) {
        int r = i / 528;
        int rem = i - r * 528;
        int c = rem >> 3;
        int cig = rem & 7;
        int hh = h + r - 1;
        int gc = c - 1;
        bf16x8 val;
#pragma unroll
        for (int j = 0; j < 8; ++j) val[j] = (__bf16)0.f;
        if ((unsigned)hh < 64u && (unsigned)gc < 64u)
            val = xs[(hh * 64 + gc) * 8 + cig];
        *(bf16x8*)&xt[(r * 66 + c) * 64 + ((cig ^ (c & 7)) * 8)] = val;
    }
    const bf16x8* wsrc = (const bf16x8*)Wt2 + (size_t)co0 * 72;
    for (int i = tid; i < 2304; i += 256) {
        int co = i / 72;
        int kc = i - co * 72;
        *(bf16x8*)&wt[co * 576 + ((kc ^ (co & 7)) * 8)] = wsrc[i];
    }
    __syncthreads();

    f32x4 acc0 = {0.f, 0.f, 0.f, 0.f};
    f32x4 acc1 = {0.f, 0.f, 0.f, 0.f};
#pragma unroll
    for (int tap = 0; tap < 9; ++tap) {
        int dh = tap / 3, dw = tap % 3;
#pragma unroll
        for (int ks = 0; ks < 2; ++ks) {
            int cig = ks * 4 + lh;
            int col = nt * 16 + lm + dw;
            bf16x8 bfr = *(const bf16x8*)&xt[(dh * 66 + col) * 64 + ((cig ^ (col & 7)) * 8)];
            int kcg = tap * 8 + cig;
            bf16x8 a0 = *(const bf16x8*)&wt[lm * 576 + ((kcg ^ (lm & 7)) * 8)];
            bf16x8 a1 = *(const bf16x8*)&wt[(16 + lm) * 576 + ((kcg ^ (lm & 7)) * 8)];
            acc0 = __builtin_amdgcn_mfma_f32_16x16x32_bf16(a0, bfr, acc0, 0, 0, 0);
            acc1 = __builtin_amdgcn_mfma_f32_16x16x32_bf16(a1, bfr, acc1, 0, 0, 0);
        }
    }

    size_t obase = (size_t)b * CO_ * NPIX + h * 64 + nt * 16 + lm;
#pragma unroll
    for (int r = 0; r < 4; ++r) {
        int cl0 = lh * 4 + r;
        float y0 = fmaxf(acc0[r] * scs[cl0] + shs[cl0], 0.f);
        local[obase + (size_t)(co0 + cl0) * NPIX] = y0;
        int cl1 = 16 + cl0;
        float y1 = fmaxf(acc1[r] * scs[cl1] + shs[cl1], 0.f);
        local[obase + (size_t)(co0 + cl1) * NPIX] = y1;
    }
}

// q projection (Cout=16), fp32
__global__ __launch_bounds__(256) void z_projqk(
    const float* __restrict__ a, const float* __restrict__ W, const float* __restrict__ bias,
    float* __restrict__ out)
{
    int i = blockIdx.x * 256 + threadIdx.x;
    int n = i & (NPIX - 1);
    int c = (i >> 12) & (CQ_ - 1);
    int b = i >> 16;
    const float* ap = a + (size_t)b * CO_ * NPIX + n;
    const float* wp = W + c * CO_;
    float acc = bias[c];
#pragma unroll 8
    for (int t = 0; t < CO_; ++t) acc += wp[t] * ap[t * NPIX];
    out[i] = acc;
}

// k projection -> transposed bf16 kT[b][n][16]
__global__ __launch_bounds__(256) void z_projkT(
    const float* __restrict__ a, const float* __restrict__ W, const float* __restrict__ bias,
    __bf16* __restrict__ kT)
{
    int i = blockIdx.x * 256 + threadIdx.x;
    int n = i & (NPIX - 1);
    int c = (i >> 12) & (CQ_ - 1);
    int b = i >> 16;
    const float* ap = a + (size_t)b * CO_ * NPIX + n;
    const float* wp = W + c * CO_;
    float acc = bias[c];
#pragma unroll 8
    for (int t = 0; t < CO_; ++t) acc += wp[t] * ap[t * NPIX];
    kT[((size_t)b * NPIX + n) * CQ_ + c] = (__bf16)acc;
}

// V2[b][n/8][c][8] bf16 (MFMA B-fragment layout)
__global__ __launch_bounds__(256) void z_projv2(
    const float* __restrict__ a, const float* __restrict__ Wv, const float* __restrict__ bv,
    __bf16* __restrict__ V2)
{
    __shared__ __bf16 wsm[128 * 130];
    int tid = threadIdx.x;
    int blk = blockIdx.x;
    int b = blk >> 8;
    int ng = blk & 255;

    for (int i = tid; i < 128 * 128; i += 256) {
        int c = i >> 7, t = i & 127;
        wsm[c * 130 + t] = (__bf16)Wv[i];
    }
    __syncthreads();

    int c = tid & 127;
    int n8 = ng * 2 + (tid >> 7);
    float acc[8];
    float bvc = bv[c];
#pragma unroll
    for (int j = 0; j < 8; ++j) acc[j] = bvc;

    const float4* a4 = (const float4*)(a + (size_t)b * CO_ * NPIX);
#pragma unroll 4
    for (int t = 0; t < 128; ++t) {
        float w = (float)wsm[c * 130 + t];
        float4 a0 = a4[t * 1024 + n8 * 2];
        float4 a1 = a4[t * 1024 + n8 * 2 + 1];
        acc[0] += w * a0.x; acc[1] += w * a0.y; acc[2] += w * a0.z; acc[3] += w * a0.w;
        acc[4] += w * a1.x; acc[5] += w * a1.y; acc[6] += w * a1.z; acc[7] += w * a1.w;
    }
    bf16x8 r;
#pragma unroll
    for (int j = 0; j < 8; ++j) r[j] = (__bf16)acc[j];
    ((bf16x8*)V2)[(size_t)b * 65536 + n8 * 128 + c] = r;
}

// MFMA flash attention, attn4 structure with MT=512 (half the barriers).
// block = (b, 16 queries); wave w owns m-cols [w*128, w*128+128) of each 512-tile.
__global__ __launch_bounds__(256) void z_attn6(
    const float* __restrict__ q, const __bf16* __restrict__ kT, const __bf16* __restrict__ V2,
    const float* __restrict__ a, const float* __restrict__ gamp, float* __restrict__ attn)
{
    __shared__ __align__(16) unsigned char smem[16640];   // p_lds 16x520 bf16; o_lds aliases
    __shared__ float wmax[4][16], wsum[4][16], fs[16];
    __bf16* p_lds = (__bf16*)smem;
    float* o_lds = (float*)smem;

    int tid = threadIdx.x;
    int b = blockIdx.x >> 8;
    int q0 = (blockIdx.x & 255) * 16;
    int l = tid & 63;
    int w = tid >> 6;
    int lm = l & 15;
    int g = l >> 4;

    bf16x8 qfrag;
#pragma unroll
    for (int j = 0; j < 8; ++j) qfrag[j] = (__bf16)0.f;
    if (g < 2) {
#pragma unroll
        for (int j = 0; j < 8; ++j)
            qfrag[j] = (__bf16)q[((size_t)b * CQ_ + g * 8 + j) * NPIX + q0 + lm];
    }

    float m_run = -1e30f, l_run = 0.f;
    f32x4 acc0 = {0.f, 0.f, 0.f, 0.f};
    f32x4 acc1 = {0.f, 0.f, 0.f, 0.f};
    int c0 = w * 32 + lm;
    int c1 = c0 + 16;
    const bf16x8* vbase = (const bf16x8*)V2 + (size_t)b * 65536;
    const __bf16* ktb = kT + (size_t)b * NPIX * CQ_;

    for (int t = 0; t < 8; ++t) {
        int m0 = t * 512;
        // QK^T: 8 m-subtiles per wave
        f32x4 sfr[8];
#pragma unroll
        for (int ms = 0; ms < 8; ++ms) {
            bf16x8 kf;
#pragma unroll
            for (int j = 0; j < 8; ++j) kf[j] = (__bf16)0.f;
            if (g < 2)
                kf = *(const bf16x8*)&ktb[(size_t)(m0 + w * 128 + ms * 16 + lm) * CQ_ + g * 8];
            f32x4 zz = {0.f, 0.f, 0.f, 0.f};
            sfr[ms] = __builtin_amdgcn_mfma_f32_16x16x32_bf16(kf, qfrag, zz, 0, 0, 0);
        }
        // row max
        float pmax = -1e30f;
#pragma unroll
        for (int ms = 0; ms < 8; ++ms)
#pragma unroll
            for (int r = 0; r < 4; ++r) pmax = fmaxf(pmax, sfr[ms][r]);
        pmax = fmaxf(pmax, __shfl_xor(pmax, 16));
        pmax = fmaxf(pmax, __shfl_xor(pmax, 32));
        if (g == 0) wmax[w][lm] = pmax;
        __syncthreads();
        float tmax = fmaxf(fmaxf(wmax[0][lm], wmax[1][lm]), fmaxf(wmax[2][lm], wmax[3][lm]));
        float nm = fmaxf(m_run, tmax);
        float f = __expf(m_run - nm);
        m_run = nm;
        if (w == 0 && g == 0) fs[lm] = f;
        // exp, pack bf16 P, partial sum
        float psum = 0.f;
#pragma unroll
        for (int ms = 0; ms < 8; ++ms) {
            float p0 = __expf(sfr[ms][0] - nm);
            float p1 = __expf(sfr[ms][1] - nm);
            float p2 = __expf(sfr[ms][2] - nm);
            float p3 = __expf(sfr[ms][3] - nm);
            psum += (p0 + p1) + (p2 + p3);
            bf16x4 pk;
            pk[0] = (__bf16)p0; pk[1] = (__bf16)p1; pk[2] = (__bf16)p2; pk[3] = (__bf16)p3;
            *(bf16x4*)&p_lds[lm * 520 + w * 128 + ms * 16 + g * 4] = pk;
        }
        psum += __shfl_xor(psum, 16);
        psum += __shfl_xor(psum, 32);
        if (g == 0) wsum[w][lm] = psum;
        __syncthreads();
        float tsum = (wsum[0][lm] + wsum[1][lm]) + (wsum[2][lm] + wsum[3][lm]);
        l_run = l_run * f + tsum;
        // rescale + PV MFMA (K=512 in 16 chunks)
        float f0 = fs[g * 4 + 0], f1 = fs[g * 4 + 1], f2 = fs[g * 4 + 2], f3 = fs[g * 4 + 3];
        acc0[0] *= f0; acc0[1] *= f1; acc0[2] *= f2; acc0[3] *= f3;
        acc1[0] *= f0; acc1[1] *= f1; acc1[2] *= f2; acc1[3] *= f3;
#pragma unroll
        for (int ks = 0; ks < 16; ++ks) {
            bf16x8 afrag = *(const bf16x8*)&p_lds[lm * 520 + ks * 32 + g * 8];
            int msv = (m0 >> 3) + ks * 4 + g;
            bf16x8 bf0 = vbase[msv * 128 + c0];
            bf16x8 bf1 = vbase[msv * 128 + c1];
            acc0 = __builtin_amdgcn_mfma_f32_16x16x32_bf16(afrag, bf0, acc0, 0, 0, 0);
            acc1 = __builtin_amdgcn_mfma_f32_16x16x32_bf16(afrag, bf1, acc1, 0, 0, 0);
        }
        __syncthreads();
    }

    // epilogue
#pragma unroll
    for (int r = 0; r < 4; ++r) {
        int qrow = g * 4 + r;
        o_lds[c0 * 17 + qrow] = acc0[r];
        o_lds[c1 * 17 + qrow] = acc1[r];
    }
    __syncthreads();
    float gam = gamp[0];
    int qi = tid & 15;
    float inv = 1.f / l_run;
#pragma unroll
    for (int j = 0; j < 8; ++j) {
        int cc = (tid >> 4) + 16 * j;
        size_t idx = ((size_t)b * CO_ + cc) * NPIX + q0 + qi;
        attn[idx] = gam * (o_lds[cc * 17 + qi] * inv) + a[idx];
    }
}

// fused gate + final, MFMA everywhere (validated round 13)
__global__ __launch_bounds__(256) void z_fuseout2(
    const float* __restrict__ local, const float* __restrict__ attn, const float* __restrict__ x,
    const __bf16* __restrict__ Wb,
    const float* __restrict__ bg, const float* __restrict__ g3, const float* __restrict__ b3n,
    const float* __restrict__ m3, const float* __restrict__ v3,
    const float* __restrict__ bfb, const float* __restrict__ g4, const float* __restrict__ b4,
    const float* __restrict__ m4, const float* __restrict__ v4,
    const float* __restrict__ rsp, float* __restrict__ out)
{
    __shared__ __align__(16) unsigned char smem[32768 + 4096];
    __bf16* sb2 = (__bf16*)smem;
    __bf16* sxT = (__bf16*)(smem + 28672);

    int tid = threadIdx.x;
    int b = blockIdx.x >> 7;
    int n0 = (blockIdx.x & 127) * 32;

#pragma unroll
    for (int p = 0; p < 4; ++p) {
        int idx = p * 256 + tid;
        int c = idx >> 3, j = idx & 7;
        float lv[4], av[4];
        *(float4*)lv = *(const float4*)(local + ((size_t)b * CO_ + c) * NPIX + n0 + j * 4);
        *(float4*)av = *(const float4*)(attn + ((size_t)b * CO_ + c) * NPIX + n0 + j * 4);
#pragma unroll
        for (int e = 0; e < 4; ++e) {
            int n = j * 4 + e;
            int k1 = 128 + c, k2 = 256 + c;
            sb2[n * 448 + (((k1 >> 3) ^ (n & 7)) << 3) + (k1 & 7)] = (__bf16)lv[e];
            sb2[n * 448 + (((k2 >> 3) ^ (n & 7)) << 3) + (k2 & 7)] = (__bf16)av[e];
        }
    }
#pragma unroll
    for (int p = 0; p < 2; ++p) {
        int idx = p * 256 + tid;
        int c = idx >> 3, j = idx & 7;
        float xv[4];
        *(float4*)xv = *(const float4*)(x + ((size_t)b * CI_ + c) * NPIX + n0 + j * 4);
#pragma unroll
        for (int e = 0; e < 4; ++e) {
            int n = j * 4 + e;
            sxT[n * 64 + (((c >> 3) ^ (n & 7)) << 3) + (c & 7)] = (__bf16)xv[e];
        }
    }
    __syncthreads();

    int l = tid & 63, w = tid >> 6;
    int lm = l & 15, g = l >> 4;
    int co0 = w * 32;
    int t7 = lm & 7;

    f32x4 p1[2][2];
#pragma unroll
    for (int cs = 0; cs < 2; ++cs) {
        float bv = bg[co0 + cs * 16 + lm];
#pragma unroll
        for (int ns = 0; ns < 2; ++ns) {
            p1[ns][cs][0] = bv; p1[ns][cs][1] = bv; p1[ns][cs][2] = bv; p1[ns][cs][3] = bv;
        }
    }
    const __bf16* Wg2 = Wb;
#pragma unroll
    for (int kc = 0; kc < 8; ++kc) {
        int ch = (16 + kc * 4 + g) ^ t7;
        bf16x8 a0 = *(const bf16x8*)&sb2[lm * 448 + ch * 8];
        bf16x8 a1 = *(const bf16x8*)&sb2[(16 + lm) * 448 + ch * 8];
        bf16x8 b0 = *(const bf16x8*)&Wg2[(size_t)(co0 + lm) * 256 + kc * 32 + g * 8];
        bf16x8 b1 = *(const bf16x8*)&Wg2[(size_t)(co0 + 16 + lm) * 256 + kc * 32 + g * 8];
        p1[0][0] = __builtin_amdgcn_mfma_f32_16x16x32_bf16(a0, b0, p1[0][0], 0, 0, 0);
        p1[0][1] = __builtin_amdgcn_mfma_f32_16x16x32_bf16(a0, b1, p1[0][1], 0, 0, 0);
        p1[1][0] = __builtin_amdgcn_mfma_f32_16x16x32_bf16(a1, b0, p1[1][0], 0, 0, 0);
        p1[1][1] = __builtin_amdgcn_mfma_f32_16x16x32_bf16(a1, b1, p1[1][1], 0, 0, 0);
    }
#pragma unroll
    for (int cs = 0; cs < 2; ++cs) {
        int co = co0 + cs * 16 + lm;
        float sc3 = rsqrtf(v3[co] + EPS_) * g3[co];
        float sh3 = b3n[co] - m3[co] * sc3;
        int kl = 128 + co, ka = 256 + co;
#pragma unroll
        for (int ns = 0; ns < 2; ++ns)
#pragma unroll
            for (int r = 0; r < 4; ++r) {
                int n = ns * 16 + g * 4 + r;
                float z = p1[ns][cs][r] * sc3 + sh3;
                float gate = 1.f / (1.f + __expf(-z));
                float lv = (float)sb2[n * 448 + (((kl >> 3) ^ (n & 7)) << 3) + (kl & 7)];
                float av = (float)sb2[n * 448 + (((ka >> 3) ^ (n & 7)) << 3) + (ka & 7)];
                float fu = gate * lv + (1.f - gate) * av;
                sb2[n * 448 + (((co >> 3) ^ (n & 7)) << 3) + (co & 7)] = (__bf16)fu;
            }
    }
    __syncthreads();

    f32x4 p2[2][2], pr[2][2];
#pragma unroll
    for (int cs = 0; cs < 2; ++cs) {
        float bv = bfb[co0 + cs * 16 + lm];
#pragma unroll
        for (int ns = 0; ns < 2; ++ns) {
            p2[ns][cs][0] = bv; p2[ns][cs][1] = bv; p2[ns][cs][2] = bv; p2[ns][cs][3] = bv;
            pr[ns][cs] = (f32x4){0.f, 0.f, 0.f, 0.f};
        }
    }
    const __bf16* Wf2 = Wb + 32768;
    const __bf16* Wr2 = Wb + 81920;
#pragma unroll
    for (int kc = 0; kc < 12; ++kc) {
        int ch = (kc * 4 + g) ^ t7;
        bf16x8 a0 = *(const bf16x8*)&sb2[lm * 448 + ch * 8];
        bf16x8 a1 = *(const bf16x8*)&sb2[(16 + lm) * 448 + ch * 8];
        bf16x8 b0 = *(const bf16x8*)&Wf2[(size_t)(co0 + lm) * 384 + kc * 32 + g * 8];
        bf16x8 b1 = *(const bf16x8*)&Wf2[(size_t)(co0 + 16 + lm) * 384 + kc * 32 + g * 8];
        p2[0][0] = __builtin_amdgcn_mfma_f32_16x16x32_bf16(a0, b0, p2[0][0], 0, 0, 0);
        p2[0][1] = __builtin_amdgcn_mfma_f32_16x16x32_bf16(a0, b1, p2[0][1], 0, 0, 0);
        p2[1][0] = __builtin_amdgcn_mfma_f32_16x16x32_bf16(a1, b0, p2[1][0], 0, 0, 0);
        p2[1][1] = __builtin_amdgcn_mfma_f32_16x16x32_bf16(a1, b1, p2[1][1], 0, 0, 0);
    }
#pragma unroll
    for (int kc = 0; kc < 2; ++kc) {
        int ch = (kc * 4 + g) ^ t7;
        bf16x8 a0 = *(const bf16x8*)&sxT[lm * 64 + ch * 8];
        bf16x8 a1 = *(const bf16x8*)&sxT[(16 + lm) * 64 + ch * 8];
        bf16x8 b0 = *(const bf16x8*)&Wr2[(size_t)(co0 + lm) * 64 + kc * 32 + g * 8];
        bf16x8 b1 = *(const bf16x8*)&Wr2[(size_t)(co0 + 16 + lm) * 64 + kc * 32 + g * 8];
        pr[0][0] = __builtin_amdgcn_mfma_f32_16x16x32_bf16(a0, b0, pr[0][0], 0, 0, 0);
        pr[0][1] = __builtin_amdgcn_mfma_f32_16x16x32_bf16(a0, b1, pr[0][1], 0, 0, 0);
        pr[1][0] = __builtin_amdgcn_mfma_f32_16x16x32_bf16(a1, b0, pr[1][0], 0, 0, 0);
        pr[1][1] = __builtin_amdgcn_mfma_f32_16x16x32_bf16(a1, b1, pr[1][1], 0, 0, 0);
    }
    __syncthreads();

    float* o_lds = (float*)smem;   // [128][36]
    float rsv = rsp[0];
#pragma unroll
    for (int cs = 0; cs < 2; ++cs) {
        int co = co0 + cs * 16 + lm;
        float sc4 = rsqrtf(v4[co] + EPS_) * g4[co];
        float sh4 = b4[co] - m4[co] * sc4;
#pragma unroll
        for (int ns = 0; ns < 2; ++ns)
#pragma unroll
            for (int r = 0; r < 4; ++r) {
                int n = ns * 16 + g * 4 + r;
                float o = fmaxf(p2[ns][cs][r] * sc4 + sh4, 0.f) + rsv * pr[ns][cs][r];
                o_lds[co * 36 + n] = o;
            }
    }
    __syncthreads();
    {
        int c = tid >> 1, h = tid & 1;
#pragma unroll
        for (int j2 = 0; j2 < 4; ++j2) {
            float4 vv = *(float4*)&o_lds[c * 36 + h * 16 + j2 * 4];
            *(float4*)(out + ((size_t)b * CO_ + c) * NPIX + n0 + h * 16 + j2 * 4) = vv;
        }
    }
}

extern "C" void kernel_launch(void* const* d_in, const int* in_sizes, int n_in,
                              void* d_out, int out_size, void* d_ws, size_t ws_size,
                              hipStream_t stream) {
    const float* x   = (const float*)d_in[0];
    const float* W3  = (const float*)d_in[1];
    const float* b3  = (const float*)d_in[2];
    const float* g1  = (const float*)d_in[3];
    const float* b1  = (const float*)d_in[4];
    const float* m1  = (const float*)d_in[5];
    const float* v1  = (const float*)d_in[6];
    const float* Wa  = (const float*)d_in[7];
    const float* ba  = (const float*)d_in[8];
    const float* g2  = (const float*)d_in[9];
    const float* b2  = (const float*)d_in[10];
    const float* m2  = (const float*)d_in[11];
    const float* v2  = (const float*)d_in[12];
    const float* Wq  = (const float*)d_in[13];
    const float* bq  = (const float*)d_in[14];
    const float* Wk  = (const float*)d_in[15];
    const float* bk  = (const float*)d_in[16];
    const float* Wv  = (const float*)d_in[17];
    const float* bv  = (const float*)d_in[18];
    const float* gam = (const float*)d_in[19];
    const float* Wg  = (const float*)d_in[20];
    const float* bg  = (const float*)d_in[21];
    const float* g3  = (const float*)d_in[22];
    const float* b3n = (const float*)d_in[23];
    const float* m3  = (const float*)d_in[24];
    const float* v3  = (const float*)d_in[25];
    const float* Wf  = (const float*)d_in[26];
    const float* bfb = (const float*)d_in[27];
    const float* g4  = (const float*)d_in[28];
    const float* b4  = (const float*)d_in[29];
    const float* m4  = (const float*)d_in[30];
    const float* v4  = (const float*)d_in[31];
    const float* Wr  = (const float*)d_in[32];
    const float* rs  = (const float*)d_in[33];

    float* ws    = (float*)d_ws;
    float* a_    = ws;                       // [0, 2M)
    float* local = ws + 2097152;             // [2M, 4M)
    float* attn  = ws + 4194304;             // [4M, 6M)
    __bf16* V2   = (__bf16*)(ws + 6291456);  // 4 MB bf16
    float* q     = ws + 7340032;             // 262,144 floats
    __bf16* kT   = (__bf16*)(ws + 7602176);  // 512 KB bf16
    __bf16* xT   = (__bf16*)(ws + 7864320);  // 2 MB bf16
    __bf16* Wt2  = (__bf16*)(ws + 8388608);  // 147 KB bf16
    __bf16* Wb   = (__bf16*)(ws + 8450048);  // 180 KB bf16

    float* out = (float*)d_out;

    z_prepx<<<256, 256, 0, stream>>>(x, xT);
    z_prepw<<<288, 256, 0, stream>>>(W3, Wt2);
    z_prepfw<<<352, 256, 0, stream>>>(Wg, Wf, Wr, Wb);
    z_proj_a4<<<2048, 256, 0, stream>>>(x, Wa, ba, g2, b2, m2, v2, a_);
    z_projqk<<<1024, 256, 0, stream>>>(a_, Wq, bq, q);
    z_projkT<<<1024, 256, 0, stream>>>(a_, Wk, bk, kT);
    z_projv2<<<1024, 256, 0, stream>>>(a_, Wv, bv, V2);
    z_attn6<<<1024, 256, 0, stream>>>(q, kT, V2, a_, gam, attn);
    z_conv3m<<<1024, 256, 0, stream>>>(xT, Wt2, b3, g1, b1, m1, v1, local);
    z_fuseout2<<<512, 256, 0, stream>>>(local, attn, x, Wb, bg, g3, b3n, m3, v3,
                                        bfb, g4, b4, m4, v4, rs, out);
}

// Round 16
// 117.685 us; speedup vs baseline: 2.0163x; 1.8302x over previous
//
#include <hip/hip_runtime.h>
#include <hip/hip_bf16.h>

#define CI_ 64
#define CO_ 128
#define NPIX 4096
#define CQ_ 16
#define EPS_ 1e-5f

typedef __attribute__((ext_vector_type(8))) __bf16 bf16x8;
typedef __attribute__((ext_vector_type(4))) __bf16 bf16x4;
typedef __attribute__((ext_vector_type(4))) float f32x4;

// transpose x -> xT[b][n][ci] bf16
__global__ __launch_bounds__(256) void z_prepx(
    const float* __restrict__ x, __bf16* __restrict__ xT)
{
    __shared__ float tl[64][65];
    int b = blockIdx.x >> 6;
    int n0 = (blockIdx.x & 63) * 64;
    int tid = threadIdx.x;
    int nn = tid & 63, c4 = tid >> 6;
#pragma unroll
    for (int p = 0; p < 16; ++p) {
        int ci = p * 4 + c4;
        tl[ci][nn] = x[((size_t)b * CI_ + ci) * NPIX + n0 + nn];
    }
    __syncthreads();
#pragma unroll
    for (int p = 0; p < 2; ++p) {
        int idx = p * 256 + tid;
        int n = idx >> 3, cig = idx & 7;
        bf16x8 vv;
#pragma unroll
        for (int j = 0; j < 8; ++j) vv[j] = (__bf16)tl[cig * 8 + j][n];
        ((bf16x8*)xT)[((size_t)b * NPIX + n0 + n) * 8 + cig] = vv;
    }
}

// W3 -> Wt2[co][tap*64+ci] bf16
__global__ __launch_bounds__(256) void z_prepw(
    const float* __restrict__ W3, __bf16* __restrict__ Wt2)
{
    int o = blockIdx.x * 256 + threadIdx.x;
    int co = o / 576;
    int r = o - co * 576;
    int tap = r >> 6;
    int ci = r & 63;
    Wt2[o] = (__bf16)W3[((size_t)co * CI_ + ci) * 9 + tap];
}

// Wg|Wf|Wr|Wa|Wq|Wk|Wv -> bf16 concatenated (118784 elems)
__global__ __launch_bounds__(256) void z_prepfw2(
    const float* __restrict__ Wg, const float* __restrict__ Wf, const float* __restrict__ Wr,
    const float* __restrict__ Wa, const float* __restrict__ Wq, const float* __restrict__ Wk,
    const float* __restrict__ Wv, __bf16* __restrict__ Wb)
{
    int i = blockIdx.x * 256 + threadIdx.x;
    if (i >= 118784) return;
    float val;
    if (i < 32768) val = Wg[i];
    else if (i < 81920) val = Wf[i - 32768];
    else if (i < 90112) val = Wr[i - 81920];
    else if (i < 98304) val = Wa[i - 90112];
    else if (i < 100352) val = Wq[i - 98304];
    else if (i < 102400) val = Wk[i - 100352];
    else val = Wv[i - 102400];
    Wb[i] = (__bf16)val;
}

// fused producer: a = relu(bn2(Wa@x)), then q/kT/V2 from a. All MFMA.
// grid: b(4) x n-tile(256 of 16) = 1024 blocks, 4 waves.
__global__ __launch_bounds__(256) void z_mega(
    const __bf16* __restrict__ xT, const __bf16* __restrict__ Wb,
    const float* __restrict__ ba, const float* __restrict__ g2, const float* __restrict__ b2,
    const float* __restrict__ m2, const float* __restrict__ v2,
    const float* __restrict__ bq, const float* __restrict__ bk, const float* __restrict__ bv,
    float* __restrict__ a, float* __restrict__ q, __bf16* __restrict__ kT, __bf16* __restrict__ V2)
{
    __shared__ __align__(16) __bf16 an[16 * 128];   // 4KB, [n][co] XOR-swizzled chunks
    int tid = threadIdx.x;
    int b = blockIdx.x >> 8;
    int n0 = (blockIdx.x & 255) * 16;
    int l = tid & 63, w = tid >> 6;
    int lm = l & 15, g = l >> 4;

    const __bf16* Wa2 = Wb + 90112;
    const __bf16* Wq2 = Wb + 98304;
    const __bf16* Wk2 = Wb + 100352;
    const __bf16* Wv2 = Wb + 102400;

    // ---- stage A: a rows [w*32, w*32+32), cols n0..n0+15 ----
    bf16x8 bx[2];
#pragma unroll
    for (int kc = 0; kc < 2; ++kc)
        bx[kc] = ((const bf16x8*)xT)[((size_t)b * NPIX + n0 + lm) * 8 + (kc * 4 + g)];
    f32x4 pa[2];
#pragma unroll
    for (int ct = 0; ct < 2; ++ct) {
#pragma unroll
        for (int r = 0; r < 4; ++r) pa[ct][r] = ba[w * 32 + ct * 16 + g * 4 + r];
#pragma unroll
        for (int kc = 0; kc < 2; ++kc) {
            bf16x8 afr = *(const bf16x8*)&Wa2[(size_t)(w * 32 + ct * 16 + lm) * 64 + kc * 32 + g * 8];
            pa[ct] = __builtin_amdgcn_mfma_f32_16x16x32_bf16(afr, bx[kc], pa[ct], 0, 0, 0);
        }
    }
#pragma unroll
    for (int ct = 0; ct < 2; ++ct) {
        bf16x4 pk;
#pragma unroll
        for (int r = 0; r < 4; ++r) {
            int co = w * 32 + ct * 16 + g * 4 + r;
            float sc = rsqrtf(v2[co] + EPS_) * g2[co];
            float sh = b2[co] - m2[co] * sc;
            float y = fmaxf(pa[ct][r] * sc + sh, 0.f);
            a[((size_t)b * CO_ + co) * NPIX + n0 + lm] = y;
            pk[r] = (__bf16)y;
        }
        int co8 = w * 4 + ct * 2 + (g >> 1);          // co>>3
        int ch = co8 ^ (lm & 7);
        *(bf16x4*)&an[lm * 128 + ch * 8 + (g & 1) * 4] = pk;
    }
    __syncthreads();

    // ---- stage B: q/kT/V2 from an ----
    bf16x8 bn[4];
#pragma unroll
    for (int kc = 0; kc < 4; ++kc) {
        int ch = (kc * 4 + g) ^ (lm & 7);
        bn[kc] = *(const bf16x8*)&an[lm * 128 + ch * 8];
    }
    // V quarter [w*32, w*32+32)
    f32x4 pv[2];
#pragma unroll
    for (int ct = 0; ct < 2; ++ct) {
#pragma unroll
        for (int r = 0; r < 4; ++r) pv[ct][r] = bv[w * 32 + ct * 16 + g * 4 + r];
#pragma unroll
        for (int kc = 0; kc < 4; ++kc) {
            bf16x8 afr = *(const bf16x8*)&Wv2[(size_t)(w * 32 + ct * 16 + lm) * 128 + kc * 32 + g * 8];
            pv[ct] = __builtin_amdgcn_mfma_f32_16x16x32_bf16(afr, bn[kc], pv[ct], 0, 0, 0);
        }
    }
    int n = n0 + lm;
#pragma unroll
    for (int ct = 0; ct < 2; ++ct)
#pragma unroll
        for (int r = 0; r < 4; ++r) {
            int c = w * 32 + ct * 16 + g * 4 + r;
            V2[(size_t)b * 524288 + (size_t)(n >> 3) * 1024 + c * 8 + (n & 7)] = (__bf16)pv[ct][r];
        }
    if (w == 0) {
        f32x4 pq;
#pragma unroll
        for (int r = 0; r < 4; ++r) pq[r] = bq[g * 4 + r];
#pragma unroll
        for (int kc = 0; kc < 4; ++kc) {
            bf16x8 afr = *(const bf16x8*)&Wq2[(size_t)lm * 128 + kc * 32 + g * 8];
            pq = __builtin_amdgcn_mfma_f32_16x16x32_bf16(afr, bn[kc], pq, 0, 0, 0);
        }
#pragma unroll
        for (int r = 0; r < 4; ++r)
            q[((size_t)b * CQ_ + g * 4 + r) * NPIX + n] = pq[r];
    } else if (w == 1) {
        f32x4 pk2;
#pragma unroll
        for (int r = 0; r < 4; ++r) pk2[r] = bk[g * 4 + r];
#pragma unroll
        for (int kc = 0; kc < 4; ++kc) {
            bf16x8 afr = *(const bf16x8*)&Wk2[(size_t)lm * 128 + kc * 32 + g * 8];
            pk2 = __builtin_amdgcn_mfma_f32_16x16x32_bf16(afr, bn[kc], pk2, 0, 0, 0);
        }
        bf16x4 kk;
#pragma unroll
        for (int r = 0; r < 4; ++r) kk[r] = (__bf16)pk2[r];
        *(bf16x4*)&kT[((size_t)b * NPIX + n) * CQ_ + g * 4] = kk;
    }
}

// MFMA implicit-GEMM conv3x3 + BN + ReLU (validated)
__global__ __launch_bounds__(256) void z_conv3m(
    const __bf16* __restrict__ xT, const __bf16* __restrict__ Wt2,
    const float* __restrict__ b3, const float* __restrict__ g,
    const float* __restrict__ bb, const float* __restrict__ m,
    const float* __restrict__ v, float* __restrict__ local)
{
    __shared__ __align__(16) __bf16 xt[3 * 66 * 64];
    __shared__ __align__(16) __bf16 wt[32 * 576];
    __shared__ float scs[32], shs[32];

    int blk = blockIdx.x;
    int b = blk >> 8;
    int h = (blk >> 2) & 63;
    int cg = blk & 3;
    int co0 = cg * 32;
    int tid = threadIdx.x;
    int l = tid & 63;
    int nt = tid >> 6;
    int lm = l & 15, lh = l >> 4;

    if (tid < 32) {
        int co = co0 + tid;
        float scv = rsqrtf(v[co] + EPS_) * g[co];
        scs[tid] = scv;
        shs[tid] = (b3[co] - m[co]) * scv + bb[co];
    }

    const bf16x8* xs = (const bf16x8*)xT + (size_t)b * (NPIX * 8);
    for (int i = tid; i < 1584; i += 256) {
        int r = i / 528;
        int rem = i - r * 528;
        int c = rem >> 3;
        int cig = rem & 7;
        int hh = h + r - 1;
        int gc = c - 1;
        bf16x8 val;
#pragma unroll
        for (int j = 0; j < 8; ++j) val[j] = (__bf16)0.f;
        if ((unsigned)hh < 64u && (unsigned)gc < 64u)
            val = xs[(hh * 64 + gc) * 8 + cig];
        *(bf16x8*)&xt[(r * 66 + c) * 64 + ((cig ^ (c & 7)) * 8)] = val;
    }
    const bf16x8* wsrc = (const bf16x8*)Wt2 + (size_t)co0 * 72;
    for (int i = tid; i < 2304; i += 256) {
        int co = i / 72;
        int kc = i - co * 72;
        *(bf16x8*)&wt[co * 576 + ((kc ^ (co & 7)) * 8)] = wsrc[i];
    }
    __syncthreads();

    f32x4 acc0 = {0.f, 0.f, 0.f, 0.f};
    f32x4 acc1 = {0.f, 0.f, 0.f, 0.f};
#pragma unroll
    for (int tap = 0; tap < 9; ++tap) {
        int dh = tap / 3, dw = tap % 3;
#pragma unroll
        for (int ks = 0; ks < 2; ++ks) {
            int cig = ks * 4 + lh;
            int col = nt * 16 + lm + dw;
            bf16x8 bfr = *(const bf16x8*)&xt[(dh * 66 + col) * 64 + ((cig ^ (col & 7)) * 8)];
            int kcg = tap * 8 + cig;
            bf16x8 a0 = *(const bf16x8*)&wt[lm * 576 + ((kcg ^ (lm & 7)) * 8)];
            bf16x8 a1 = *(const bf16x8*)&wt[(16 + lm) * 576 + ((kcg ^ (lm & 7)) * 8)];
            acc0 = __builtin_amdgcn_mfma_f32_16x16x32_bf16(a0, bfr, acc0, 0, 0, 0);
            acc1 = __builtin_amdgcn_mfma_f32_16x16x32_bf16(a1, bfr, acc1, 0, 0, 0);
        }
    }

    size_t obase = (size_t)b * CO_ * NPIX + h * 64 + nt * 16 + lm;
#pragma unroll
    for (int r = 0; r < 4; ++r) {
        int cl0 = lh * 4 + r;
        float y0 = fmaxf(acc0[r] * scs[cl0] + shs[cl0], 0.f);
        local[obase + (size_t)(co0 + cl0) * NPIX] = y0;
        int cl1 = 16 + cl0;
        float y1 = fmaxf(acc1[r] * scs[cl1] + shs[cl1], 0.f);
        local[obase + (size_t)(co0 + cl1) * NPIX] = y1;
    }
}

// MFMA flash attention (round-12 validated z_attn4, 64 us)
__global__ __launch_bounds__(256) void z_attn4(
    const float* __restrict__ q, const __bf16* __restrict__ kT, const __bf16* __restrict__ V2,
    const float* __restrict__ a, const float* __restrict__ gamp, float* __restrict__ attn)
{
    __shared__ __align__(16) unsigned char smem[8704];
    __shared__ float wmax[4][16], wsum[4][16], fs[16];
    __bf16* p_lds = (__bf16*)smem;
    float* o_lds = (float*)smem;

    int tid = threadIdx.x;
    int b = blockIdx.x >> 8;
    int q0 = (blockIdx.x & 255) * 16;
    int l = tid & 63;
    int w = tid >> 6;
    int lm = l & 15;
    int g = l >> 4;

    bf16x8 qfrag;
#pragma unroll
    for (int j = 0; j < 8; ++j) qfrag[j] = (__bf16)0.f;
    if (g < 2) {
#pragma unroll
        for (int j = 0; j < 8; ++j)
            qfrag[j] = (__bf16)q[((size_t)b * CQ_ + g * 8 + j) * NPIX + q0 + lm];
    }

    float m_run = -1e30f, l_run = 0.f;
    f32x4 acc0 = {0.f, 0.f, 0.f, 0.f};
    f32x4 acc1 = {0.f, 0.f, 0.f, 0.f};
    int c0 = w * 32 + lm;
    int c1 = c0 + 16;
    const bf16x8* vbase = (const bf16x8*)V2 + (size_t)b * 65536;
    const __bf16* ktb = kT + (size_t)b * NPIX * CQ_;

    for (int t = 0; t < 16; ++t) {
        int m0 = t * 256;
        f32x4 sfr[4];
#pragma unroll
        for (int ms = 0; ms < 4; ++ms) {
            bf16x8 kf;
#pragma unroll
            for (int j = 0; j < 8; ++j) kf[j] = (__bf16)0.f;
            if (g < 2)
                kf = *(const bf16x8*)&ktb[(size_t)(m0 + w * 64 + ms * 16 + lm) * CQ_ + g * 8];
            f32x4 zz = {0.f, 0.f, 0.f, 0.f};
            sfr[ms] = __builtin_amdgcn_mfma_f32_16x16x32_bf16(kf, qfrag, zz, 0, 0, 0);
        }
        float pmax = -1e30f;
#pragma unroll
        for (int ms = 0; ms < 4; ++ms)
#pragma unroll
            for (int r = 0; r < 4; ++r) pmax = fmaxf(pmax, sfr[ms][r]);
        pmax = fmaxf(pmax, __shfl_xor(pmax, 16));
        pmax = fmaxf(pmax, __shfl_xor(pmax, 32));
        if (g == 0) wmax[w][lm] = pmax;
        __syncthreads();
        float tmax = fmaxf(fmaxf(wmax[0][lm], wmax[1][lm]), fmaxf(wmax[2][lm], wmax[3][lm]));
        float nm = fmaxf(m_run, tmax);
        float f = __expf(m_run - nm);
        m_run = nm;
        if (w == 0 && g == 0) fs[lm] = f;
        float psum = 0.f;
#pragma unroll
        for (int ms = 0; ms < 4; ++ms) {
            float p0 = __expf(sfr[ms][0] - nm);
            float p1 = __expf(sfr[ms][1] - nm);
            float p2 = __expf(sfr[ms][2] - nm);
            float p3 = __expf(sfr[ms][3] - nm);
            psum += (p0 + p1) + (p2 + p3);
            bf16x4 pk;
            pk[0] = (__bf16)p0; pk[1] = (__bf16)p1; pk[2] = (__bf16)p2; pk[3] = (__bf16)p3;
            *(bf16x4*)&p_lds[lm * 264 + w * 64 + ms * 16 + g * 4] = pk;
        }
        psum += __shfl_xor(psum, 16);
        psum += __shfl_xor(psum, 32);
        if (g == 0) wsum[w][lm] = psum;
        __syncthreads();
        float tsum = (wsum[0][lm] + wsum[1][lm]) + (wsum[2][lm] + wsum[3][lm]);
        l_run = l_run * f + tsum;
        float f0 = fs[g * 4 + 0], f1 = fs[g * 4 + 1], f2 = fs[g * 4 + 2], f3 = fs[g * 4 + 3];
        acc0[0] *= f0; acc0[1] *= f1; acc0[2] *= f2; acc0[3] *= f3;
        acc1[0] *= f0; acc1[1] *= f1; acc1[2] *= f2; acc1[3] *= f3;
#pragma unroll
        for (int ks = 0; ks < 8; ++ks) {
            bf16x8 afrag = *(const bf16x8*)&p_lds[lm * 264 + ks * 32 + g * 8];
            int msv = (m0 >> 3) + ks * 4 + g;
            bf16x8 bf0 = vbase[msv * 128 + c0];
            bf16x8 bf1 = vbase[msv * 128 + c1];
            acc0 = __builtin_amdgcn_mfma_f32_16x16x32_bf16(afrag, bf0, acc0, 0, 0, 0);
            acc1 = __builtin_amdgcn_mfma_f32_16x16x32_bf16(afrag, bf1, acc1, 0, 0, 0);
        }
        __syncthreads();
    }

#pragma unroll
    for (int r = 0; r < 4; ++r) {
        int qrow = g * 4 + r;
        o_lds[c0 * 17 + qrow] = acc0[r];
        o_lds[c1 * 17 + qrow] = acc1[r];
    }
    __syncthreads();
    float gam = gamp[0];
    int qi = tid & 15;
    float inv = 1.f / l_run;
#pragma unroll
    for (int j = 0; j < 8; ++j) {
        int cc = (tid >> 4) + 16 * j;
        size_t idx = ((size_t)b * CO_ + cc) * NPIX + q0 + qi;
        attn[idx] = gam * (o_lds[cc * 17 + qi] * inv) + a[idx];
    }
}

// fused gate + final, MFMA everywhere (validated)
__global__ __launch_bounds__(256) void z_fuseout2(
    const float* __restrict__ local, const float* __restrict__ attn, const float* __restrict__ x,
    const __bf16* __restrict__ Wb,
    const float* __restrict__ bg, const float* __restrict__ g3, const float* __restrict__ b3n,
    const float* __restrict__ m3, const float* __restrict__ v3,
    const float* __restrict__ bfb, const float* __restrict__ g4, const float* __restrict__ b4,
    const float* __restrict__ m4, const float* __restrict__ v4,
    const float* __restrict__ rsp, float* __restrict__ out)
{
    __shared__ __align__(16) unsigned char smem[32768 + 4096];
    __bf16* sb2 = (__bf16*)smem;
    __bf16* sxT = (__bf16*)(smem + 28672);

    int tid = threadIdx.x;
    int b = blockIdx.x >> 7;
    int n0 = (blockIdx.x & 127) * 32;

#pragma unroll
    for (int p = 0; p < 4; ++p) {
        int idx = p * 256 + tid;
        int c = idx >> 3, j = idx & 7;
        float lv[4], av[4];
        *(float4*)lv = *(const float4*)(local + ((size_t)b * CO_ + c) * NPIX + n0 + j * 4);
        *(float4*)av = *(const float4*)(attn + ((size_t)b * CO_ + c) * NPIX + n0 + j * 4);
#pragma unroll
        for (int e = 0; e < 4; ++e) {
            int n = j * 4 + e;
            int k1 = 128 + c, k2 = 256 + c;
            sb2[n * 448 + (((k1 >> 3) ^ (n & 7)) << 3) + (k1 & 7)] = (__bf16)lv[e];
            sb2[n * 448 + (((k2 >> 3) ^ (n & 7)) << 3) + (k2 & 7)] = (__bf16)av[e];
        }
    }
#pragma unroll
    for (int p = 0; p < 2; ++p) {
        int idx = p * 256 + tid;
        int c = idx >> 3, j = idx & 7;
        float xv[4];
        *(float4*)xv = *(const float4*)(x + ((size_t)b * CI_ + c) * NPIX + n0 + j * 4);
#pragma unroll
        for (int e = 0; e < 4; ++e) {
            int n = j * 4 + e;
            sxT[n * 64 + (((c >> 3) ^ (n & 7)) << 3) + (c & 7)] = (__bf16)xv[e];
        }
    }
    __syncthreads();

    int l = tid & 63, w = tid >> 6;
    int lm = l & 15, g = l >> 4;
    int co0 = w * 32;
    int t7 = lm & 7;

    f32x4 p1[2][2];
#pragma unroll
    for (int cs = 0; cs < 2; ++cs) {
        float bv = bg[co0 + cs * 16 + lm];
#pragma unroll
        for (int ns = 0; ns < 2; ++ns) {
            p1[ns][cs][0] = bv; p1[ns][cs][1] = bv; p1[ns][cs][2] = bv; p1[ns][cs][3] = bv;
        }
    }
    const __bf16* Wg2 = Wb;
#pragma unroll
    for (int kc = 0; kc < 8; ++kc) {
        int ch = (16 + kc * 4 + g) ^ t7;
        bf16x8 a0 = *(const bf16x8*)&sb2[lm * 448 + ch * 8];
        bf16x8 a1 = *(const bf16x8*)&sb2[(16 + lm) * 448 + ch * 8];
        bf16x8 b0 = *(const bf16x8*)&Wg2[(size_t)(co0 + lm) * 256 + kc * 32 + g * 8];
        bf16x8 b1 = *(const bf16x8*)&Wg2[(size_t)(co0 + 16 + lm) * 256 + kc * 32 + g * 8];
        p1[0][0] = __builtin_amdgcn_mfma_f32_16x16x32_bf16(a0, b0, p1[0][0], 0, 0, 0);
        p1[0][1] = __builtin_amdgcn_mfma_f32_16x16x32_bf16(a0, b1, p1[0][1], 0, 0, 0);
        p1[1][0] = __builtin_amdgcn_mfma_f32_16x16x32_bf16(a1, b0, p1[1][0], 0, 0, 0);
        p1[1][1] = __builtin_amdgcn_mfma_f32_16x16x32_bf16(a1, b1, p1[1][1], 0, 0, 0);
    }
#pragma unroll
    for (int cs = 0; cs < 2; ++cs) {
        int co = co0 + cs * 16 + lm;
        float sc3 = rsqrtf(v3[co] + EPS_) * g3[co];
        float sh3 = b3n[co] - m3[co] * sc3;
        int kl = 128 + co, ka = 256 + co;
#pragma unroll
        for (int ns = 0; ns < 2; ++ns)
#pragma unroll
            for (int r = 0; r < 4; ++r) {
                int n = ns * 16 + g * 4 + r;
                float z = p1[ns][cs][r] * sc3 + sh3;
                float gate = 1.f / (1.f + __expf(-z));
                float lv = (float)sb2[n * 448 + (((kl >> 3) ^ (n & 7)) << 3) + (kl & 7)];
                float av = (float)sb2[n * 448 + (((ka >> 3) ^ (n & 7)) << 3) + (ka & 7)];
                float fu = gate * lv + (1.f - gate) * av;
                sb2[n * 448 + (((co >> 3) ^ (n & 7)) << 3) + (co & 7)] = (__bf16)fu;
            }
    }
    __syncthreads();

    f32x4 p2[2][2], pr[2][2];
#pragma unroll
    for (int cs = 0; cs < 2; ++cs) {
        float bv = bfb[co0 + cs * 16 + lm];
#pragma unroll
        for (int ns = 0; ns < 2; ++ns) {
            p2[ns][cs][0] = bv; p2[ns][cs][1] = bv; p2[ns][cs][2] = bv; p2[ns][cs][3] = bv;
            pr[ns][cs] = (f32x4){0.f, 0.f, 0.f, 0.f};
        }
    }
    const __bf16* Wf2 = Wb + 32768;
    const __bf16* Wr2 = Wb + 81920;
#pragma unroll
    for (int kc = 0; kc < 12; ++kc) {
        int ch = (kc * 4 + g) ^ t7;
        bf16x8 a0 = *(const bf16x8*)&sb2[lm * 448 + ch * 8];
        bf16x8 a1 = *(const bf16x8*)&sb2[(16 + lm) * 448 + ch * 8];
        bf16x8 b0 = *(const bf16x8*)&Wf2[(size_t)(co0 + lm) * 384 + kc * 32 + g * 8];
        bf16x8 b1 = *(const bf16x8*)&Wf2[(size_t)(co0 + 16 + lm) * 384 + kc * 32 + g * 8];
        p2[0][0] = __builtin_amdgcn_mfma_f32_16x16x32_bf16(a0, b0, p2[0][0], 0, 0, 0);
        p2[0][1] = __builtin_amdgcn_mfma_f32_16x16x32_bf16(a0, b1, p2[0][1], 0, 0, 0);
        p2[1][0] = __builtin_amdgcn_mfma_f32_16x16x32_bf16(a1, b0, p2[1][0], 0, 0, 0);
        p2[1][1] = __builtin_amdgcn_mfma_f32_16x16x32_bf16(a1, b1, p2[1][1], 0, 0, 0);
    }
#pragma unroll
    for (int kc = 0; kc < 2; ++kc) {
        int ch = (kc * 4 + g) ^ t7;
        bf16x8 a0 = *(const bf16x8*)&sxT[lm * 64 + ch * 8];
        bf16x8 a1 = *(const bf16x8*)&sxT[(16 + lm) * 64 + ch * 8];
        bf16x8 b0 = *(const bf16x8*)&Wr2[(size_t)(co0 + lm) * 64 + kc * 32 + g * 8];
        bf16x8 b1 = *(const bf16x8*)&Wr2[(size_t)(co0 + 16 + lm) * 64 + kc * 32 + g * 8];
        pr[0][0] = __builtin_amdgcn_mfma_f32_16x16x32_bf16(a0, b0, pr[0][0], 0, 0, 0);
        pr[0][1] = __builtin_amdgcn_mfma_f32_16x16x32_bf16(a0, b1, pr[0][1], 0, 0, 0);
        pr[1][0] = __builtin_amdgcn_mfma_f32_16x16x32_bf16(a1, b0, pr[1][0], 0, 0, 0);
        pr[1][1] = __builtin_amdgcn_mfma_f32_16x16x32_bf16(a1, b1, pr[1][1], 0, 0, 0);
    }
    __syncthreads();

    float* o_lds = (float*)smem;   // [128][36]
    float rsv = rsp[0];
#pragma unroll
    for (int cs = 0; cs < 2; ++cs) {
        int co = co0 + cs * 16 + lm;
        float sc4 = rsqrtf(v4[co] + EPS_) * g4[co];
        float sh4 = b4[co] - m4[co] * sc4;
#pragma unroll
        for (int ns = 0; ns < 2; ++ns)
#pragma unroll
            for (int r = 0; r < 4; ++r) {
                int n = ns * 16 + g * 4 + r;
                float o = fmaxf(p2[ns][cs][r] * sc4 + sh4, 0.f) + rsv * pr[ns][cs][r];
                o_lds[co * 36 + n] = o;
            }
    }
    __syncthreads();
    {
        int c = tid >> 1, h = tid & 1;
#pragma unroll
        for (int j2 = 0; j2 < 4; ++j2) {
            float4 vv = *(float4*)&o_lds[c * 36 + h * 16 + j2 * 4];
            *(float4*)(out + ((size_t)b * CO_ + c) * NPIX + n0 + h * 16 + j2 * 4) = vv;
        }
    }
}

extern "C" void kernel_launch(void* const* d_in, const int* in_sizes, int n_in,
                              void* d_out, int out_size, void* d_ws, size_t ws_size,
                              hipStream_t stream) {
    const float* x   = (const float*)d_in[0];
    const float* W3  = (const float*)d_in[1];
    const float* b3  = (const float*)d_in[2];
    const float* g1  = (const float*)d_in[3];
    const float* b1  = (const float*)d_in[4];
    const float* m1  = (const float*)d_in[5];
    const float* v1  = (const float*)d_in[6];
    const float* Wa  = (const float*)d_in[7];
    const float* ba  = (const float*)d_in[8];
    const float* g2  = (const float*)d_in[9];
    const float* b2  = (const float*)d_in[10];
    const float* m2  = (const float*)d_in[11];
    const float* v2  = (const float*)d_in[12];
    const float* Wq  = (const float*)d_in[13];
    const float* bq  = (const float*)d_in[14];
    const float* Wk  = (const float*)d_in[15];
    const float* bk  = (const float*)d_in[16];
    const float* Wv  = (const float*)d_in[17];
    const float* bv  = (const float*)d_in[18];
    const float* gam = (const float*)d_in[19];
    const float* Wg  = (const float*)d_in[20];
    const float* bg  = (const float*)d_in[21];
    const float* g3  = (const float*)d_in[22];
    const float* b3n = (const float*)d_in[23];
    const float* m3  = (const float*)d_in[24];
    const float* v3  = (const float*)d_in[25];
    const float* Wf  = (const float*)d_in[26];
    const float* bfb = (const float*)d_in[27];
    const float* g4  = (const float*)d_in[28];
    const float* b4  = (const float*)d_in[29];
    const float* m4  = (const float*)d_in[30];
    const float* v4  = (const float*)d_in[31];
    const float* Wr  = (const float*)d_in[32];
    const float* rs  = (const float*)d_in[33];

    float* ws    = (float*)d_ws;
    float* a_    = ws;                       // [0, 2M)
    float* local = ws + 2097152;             // [2M, 4M)
    float* attn  = ws + 4194304;             // [4M, 6M)
    __bf16* V2   = (__bf16*)(ws + 6291456);  // 4 MB bf16
    float* q     = ws + 7340032;             // 262,144 floats
    __bf16* kT   = (__bf16*)(ws + 7602176);  // 512 KB bf16
    __bf16* xT   = (__bf16*)(ws + 7864320);  // 2 MB bf16
    __bf16* Wt2  = (__bf16*)(ws + 8388608);  // 147 KB bf16
    __bf16* Wb   = (__bf16*)(ws + 8450048);  // 232 KB bf16 (118784 elems)

    float* out = (float*)d_out;

    z_prepx<<<256, 256, 0, stream>>>(x, xT);
    z_prepw<<<288, 256, 0, stream>>>(W3, Wt2);
    z_prepfw2<<<464, 256, 0, stream>>>(Wg, Wf, Wr, Wa, Wq, Wk, Wv, Wb);
    z_mega<<<1024, 256, 0, stream>>>(xT, Wb, ba, g2, b2, m2, v2, bq, bk, bv, a_, q, kT, V2);
    z_attn4<<<1024, 256, 0, stream>>>(q, kT, V2, a_, gam, attn);
    z_conv3m<<<1024, 256, 0, stream>>>(xT, Wt2, b3, g1, b1, m1, v1, local);
    z_fuseout2<<<512, 256, 0, stream>>>(local, attn, x, Wb, bg, g3, b3n, m3, v3,
                                        bfb, g4, b4, m4, v4, rs, out);
}